// Round 14
// baseline (35.174 us; speedup 1.0000x reference)
//
#include <hip/hip_runtime.h>

// Constrained sparsemax: p = clip(z - tau, 0, u), tau s.t. sum p = 1.
// R13 structure (best measured 32.2us): 8192 one-wave blocks, probe-narrowed
// bracket, secant phase-1 on f via med3 (one DPP chain/iter), f64
// segment-Newton polish on the GLOBAL bracket, f32 epilogue with f64 region
// compares, NT stores.
// R14 adds: SECOND probe round (uniform 1/5 subdivision of the round-1
// interval; one classify + one interleaved DPP chain ~= 1.5 secant iters,
// saves ~3) and carries TRUE g-values at the bracket endpoints from the
// probe rounds so the secant seeds from a real false-position point.

typedef float vfloat4 __attribute__((ext_vector_type(4)));

template<int CTRL>
__device__ __forceinline__ float dpp_zero(float v) {   // invalid lanes -> 0
  return __builtin_bit_cast(float,
    __builtin_amdgcn_update_dpp(0, __builtin_bit_cast(int, v), CTRL, 0xf, 0xf, true));
}
template<int CTRL>
__device__ __forceinline__ float dpp_ident(float v, float ident) { // invalid -> ident
  return __builtin_bit_cast(float,
    __builtin_amdgcn_update_dpp(__builtin_bit_cast(int, ident),
                                __builtin_bit_cast(int, v), CTRL, 0xf, 0xf, false));
}
__device__ __forceinline__ float rl63(float v) {
  return __builtin_bit_cast(float,
    __builtin_amdgcn_readlane(__builtin_bit_cast(int, v), 63));
}

__device__ __forceinline__ float wave_sum(float v) {
  v += dpp_zero<0x111>(v); v += dpp_zero<0x112>(v); v += dpp_zero<0x114>(v);
  v += dpp_zero<0x118>(v); v += dpp_zero<0x142>(v); v += dpp_zero<0x143>(v);
  return rl63(v);
}
// Four interleaved full-wave sums (per-level round-robin hides chain latency).
__device__ __forceinline__ void wave_sum4(float& a, float& b, float& c, float& d) {
#define SUM4_STEP(CT) \
  a += dpp_zero<CT>(a); b += dpp_zero<CT>(b); c += dpp_zero<CT>(c); d += dpp_zero<CT>(d);
  SUM4_STEP(0x111) SUM4_STEP(0x112) SUM4_STEP(0x114)
  SUM4_STEP(0x118) SUM4_STEP(0x142) SUM4_STEP(0x143)
#undef SUM4_STEP
  a = rl63(a); b = rl63(b); c = rl63(c); d = rl63(d);
}
// init: two maxes + one sum, chains interleaved per level
__device__ __forceinline__ void wave_mms(float& a, float& b, float& s) {
  const float NI = -3.4028235e38f;
#define MMS_STEP(CT) \
  a = fmaxf(a, dpp_ident<CT>(a, NI)); b = fmaxf(b, dpp_ident<CT>(b, NI)); \
  s += dpp_zero<CT>(s);
  MMS_STEP(0x111) MMS_STEP(0x112) MMS_STEP(0x114)
  MMS_STEP(0x118) MMS_STEP(0x142) MMS_STEP(0x143)
#undef MMS_STEP
  a = rl63(a); b = rl63(b); s = rl63(s);
}
// phase 2: one f64 sum + one f32 sum, interleaved
__device__ __forceinline__ void wave_sumd_f(double& A, float& c) {
#define SUMD_STEP(CT) { \
  unsigned long long xa = __builtin_bit_cast(unsigned long long, A); \
  int al = __builtin_amdgcn_update_dpp(0, (int)(unsigned)xa, CT, 0xf, 0xf, true); \
  int ah = __builtin_amdgcn_update_dpp(0, (int)(xa >> 32),   CT, 0xf, 0xf, true); \
  c += dpp_zero<CT>(c); \
  A += __builtin_bit_cast(double, ((unsigned long long)(unsigned)ah << 32) | (unsigned)al); }
  SUMD_STEP(0x111) SUMD_STEP(0x112) SUMD_STEP(0x114)
  SUMD_STEP(0x118) SUMD_STEP(0x142) SUMD_STEP(0x143)
#undef SUMD_STEP
  { unsigned long long x = __builtin_bit_cast(unsigned long long, A);
    int l = __builtin_amdgcn_readlane((int)(unsigned)x, 63);
    int h = __builtin_amdgcn_readlane((int)(x >> 32), 63);
    A = __builtin_bit_cast(double, ((unsigned long long)(unsigned)h << 32) | (unsigned)l); }
  c = rl63(c);
}

__global__ __launch_bounds__(64)
void csparsemax_kernel(const float* __restrict__ z, const float* __restrict__ u,
                       float* __restrict__ out, int B) {
  constexpr int K = 1024;
  const int lane = threadIdx.x & 63;
  const int row = blockIdx.x;
  if (row >= B) return;
  const size_t base = (size_t)row * (size_t)K;

  // --- load 16 elems/lane as 4x float4, coalesced ---
  float zf[16], uf[16];
  const vfloat4* z4p = (const vfloat4*)(z + base);
  const vfloat4* u4p = (const vfloat4*)(u + base);
  #pragma unroll
  for (int j = 0; j < 4; ++j) {
    vfloat4 a = z4p[j * 64 + lane];
    vfloat4 b = u4p[j * 64 + lane];
    zf[j*4+0] = a.x; zf[j*4+1] = a.y; zf[j*4+2] = a.z; zf[j*4+3] = a.w;
    uf[j*4+0] = b.x; uf[j*4+1] = b.y; uf[j*4+2] = b.z; uf[j*4+3] = b.w;
  }

  // --- bracket [lo,hi] + sum(u): g(lo)=su-1 >= 0 > -1 = g(hi) ---
  float a = -3.4028235e38f, m = -3.4028235e38f, su = 0.f;
  #pragma unroll
  for (int t = 0; t < 16; ++t) {
    a = fmaxf(a, uf[t] - zf[t]);    // lo = -max(u-z) = min(z-u)
    m = fmaxf(m, zf[t]);
    su += uf[t];
  }
  wave_mms(a, m, su);
  float lo = -a, hi = m;
  float gl = su - 1.f;              // true g(lo)
  float gh = -1.f;                  // true g(hi)
  const double glo = (double)lo, ghi = (double)hi;

  // --- probe round 1: geometric near hi (root has few active elements) ---
  {
    const float w = hi - lo;
    const float p1 = hi - 0.00390625f * w;   // hi - w/256
    const float p2 = hi - 0.015625f   * w;   // hi - w/64
    const float p3 = hi - 0.0625f     * w;   // hi - w/16
    const float p4 = hi - 0.25f       * w;   // hi - w/4
    float A1 = 0.f, A2 = 0.f, A3 = 0.f, A4 = 0.f;
    #pragma unroll
    for (int t = 0; t < 16; ++t) {
      A1 += fminf(fmaxf(zf[t] - p1, 0.f), uf[t]);
      A2 += fminf(fmaxf(zf[t] - p2, 0.f), uf[t]);
      A3 += fminf(fmaxf(zf[t] - p3, 0.f), uf[t]);
      A4 += fminf(fmaxf(zf[t] - p4, 0.f), uf[t]);
    }
    wave_sum4(A1, A2, A3, A4);
    const float g1 = A1 - 1.f, g2 = A2 - 1.f, g3 = A3 - 1.f, g4 = A4 - 1.f;
    // g non-increasing in tau; probes ordered p1 > p2 > p3 > p4
    if (g1 >= 0.f)      { lo = p1; gl = g1; }
    else if (g2 >= 0.f) { lo = p2; gl = g2; hi = p1; gh = g1; }
    else if (g3 >= 0.f) { lo = p3; gl = g3; hi = p2; gh = g2; }
    else if (g4 >= 0.f) { lo = p4; gl = g4; hi = p3; gh = g3; }
    else                {                   hi = p4; gh = g4; }
  }

  // --- probe round 2: uniform 1/5 subdivision of the narrowed bracket ---
  {
    const float w2 = hi - lo;
    const float q1 = lo + 0.2f * w2;
    const float q2 = lo + 0.4f * w2;
    const float q3 = lo + 0.6f * w2;
    const float q4 = lo + 0.8f * w2;
    float A1 = 0.f, A2 = 0.f, A3 = 0.f, A4 = 0.f;
    #pragma unroll
    for (int t = 0; t < 16; ++t) {
      A1 += fminf(fmaxf(zf[t] - q1, 0.f), uf[t]);
      A2 += fminf(fmaxf(zf[t] - q2, 0.f), uf[t]);
      A3 += fminf(fmaxf(zf[t] - q3, 0.f), uf[t]);
      A4 += fminf(fmaxf(zf[t] - q4, 0.f), uf[t]);
    }
    wave_sum4(A1, A2, A3, A4);
    const float g1 = A1 - 1.f, g2 = A2 - 1.f, g3 = A3 - 1.f, g4 = A4 - 1.f;
    // q1 < q2 < q3 < q4, g(q1) >= g(q2) >= g(q3) >= g(q4)
    if (g1 < 0.f)       { hi = q1; gh = g1; }
    else if (g2 < 0.f)  { lo = q1; gl = g1; hi = q2; gh = g2; }
    else if (g3 < 0.f)  { lo = q2; gl = g2; hi = q3; gh = g3; }
    else if (g4 < 0.f)  { lo = q3; gl = g3; hi = q4; gh = g4; }
    else                { lo = q4; gl = g4; }
  }

  // --- phase 1: secant on g(tau) = sum med3(z-tau,0,u) - 1, seeded with
  //     the TRUE endpoint values (false-position start) ---
  float t_prev = hi, g_prev = gh;
  float tau = (lo * gh - hi * gl) / (gh - gl);
  if (!(tau > lo && tau < hi)) tau = 0.5f * (lo + hi);
  for (int it = 0; it < 48; ++it) {
    float f0 = 0.f, f1 = 0.f, f2 = 0.f, f3 = 0.f;
    #pragma unroll
    for (int t = 0; t < 16; t += 4) {            // v_med3_f32 per elem
      f0 += fminf(fmaxf(zf[t+0] - tau, 0.f), uf[t+0]);
      f1 += fminf(fmaxf(zf[t+1] - tau, 0.f), uf[t+1]);
      f2 += fminf(fmaxf(zf[t+2] - tau, 0.f), uf[t+2]);
      f3 += fminf(fmaxf(zf[t+3] - tau, 0.f), uf[t+3]);
    }
    float g = wave_sum((f0 + f1) + (f2 + f3)) - 1.f;
    if (g == 0.f) break;
    if (g > 0.f) lo = tau; else hi = tau;
    // secant through (t_prev,g_prev),(tau,g); out-of-bracket -> midpoint
    float cand = (tau * g_prev - t_prev * g) / (g_prev - g);
    t_prev = tau; g_prev = g;
    float next = (cand > lo && cand < hi) ? cand : 0.5f * (lo + hi);
    if (next == tau) break;                      // f32 resolution reached
    tau = next;
  }

  // --- phase 2: f64 segment-Newton polish, GLOBAL bracket (exactness) ---
  double dlo = glo, dhi = ghi, taud = (double)tau;
  for (int it = 0; it < 24; ++it) {
    double Sd = 0.0;
    float Cf = 0.f;                              // count exact in f32
    #pragma unroll
    for (int t = 0; t < 16; ++t) {
      double x = (double)zf[t] - taud;
      double ud = (double)uf[t];
      if (x >= ud)      { Sd += ud; }
      else if (x > 0.0) { Sd += (double)zf[t]; Cf += 1.f; }
    }
    wave_sumd_f(Sd, Cf);
    double C = (double)Cf;
    double f = Sd - C * taud;
    if (f == 1.0 && C > 0.5) break;
    if (f > 1.0) dlo = taud; else dhi = taud;
    double next;
    if (C > 0.5) {
      double cand = (Sd - 1.0) / C;              // exact segment root
      if (cand == taud) break;
      next = (cand > dlo && cand < dhi) ? cand : 0.5 * (dlo + dhi);
    } else {
      next = 0.5 * (dlo + dhi);
    }
    if (next == taud) break;
    taud = next;
  }

  // --- epilogue: p/val in f32, regions via f64 compares, NT stores ---
  float* out_p = out;
  float* out_r = out + (size_t)B * (size_t)K;
  float* out_t = out + 2ull * (size_t)B * (size_t)K;
  float* out_v = out_t + B;

  const float tf = (float)taud;
  float vloc = 0.f;
  #pragma unroll
  for (int j = 0; j < 4; ++j) {
    vfloat4 p4v, r4v;
    #pragma unroll
    for (int q = 0; q < 4; ++q) {
      int t = j * 4 + q;
      float pf = fminf(fmaxf(zf[t] - tf, 0.f), uf[t]);   // v_med3_f32
      float d = pf - zf[t];
      vloc = fmaf(d, d, vloc);
      double xd = (double)zf[t] - taud;                  // numpy-exact bounds
      float rg = (xd <= 0.0) ? 0.f : ((xd >= (double)uf[t]) ? 2.f : 1.f);
      p4v[q] = pf;
      r4v[q] = rg;
    }
    __builtin_nontemporal_store(p4v, &((vfloat4*)(out_p + base))[j * 64 + lane]);
    __builtin_nontemporal_store(r4v, &((vfloat4*)(out_r + base))[j * 64 + lane]);
  }

  float vtot = wave_sum(vloc);
  if (lane == 0) {
    out_t[row] = tf;
    out_v[row] = 0.5f * vtot;
  }
}

extern "C" void kernel_launch(void* const* d_in, const int* in_sizes, int n_in,
                              void* d_out, int out_size, void* d_ws, size_t ws_size,
                              hipStream_t stream) {
  const float* z = (const float*)d_in[0];
  const float* u = (const float*)d_in[1];
  float* out = (float*)d_out;
  const int K = 1024;
  const int B = in_sizes[0] / K;
  csparsemax_kernel<<<B, 64, 0, stream>>>(z, u, out, B);
}

// Round 15
// 31.250 us; speedup vs baseline: 1.1256x; 1.1256x over previous
//
#include <hip/hip_runtime.h>

// Constrained sparsemax: p = clip(z - tau, 0, u), tau s.t. sum p = 1.
// R13 structure (best measured 32.2us): 8192 one-wave blocks, probe-narrowed
// bracket, secant phase-1 on f via med3 (one DPP chain/iter), f64
// segment-Newton polish on the GLOBAL bracket, f32 epilogue with f64 region
// compares, NT stores.
// R15 change: ABSOLUTE probes {3.10,2.80,2.55,2.25} (distribution-informed:
// root tau* ~ 2.5-2.8 for z~N(0,1),K=1024; R13's hi-relative geometric probes
// left the typical root in a width-1.5 window). Absolute probes don't depend
// on hi, so the probe classify FUSES with the init classify and all six
// reductions (2 maxes + 4 probe sums) interleave into ONE serial DPP chain.
// Correctness never depends on probe placement: probes only narrow on a true
// sign flip, and phase 2 re-solves from the GLOBAL bracket regardless.

typedef float vfloat4 __attribute__((ext_vector_type(4)));

template<int CTRL>
__device__ __forceinline__ float dpp_zero(float v) {   // invalid lanes -> 0
  return __builtin_bit_cast(float,
    __builtin_amdgcn_update_dpp(0, __builtin_bit_cast(int, v), CTRL, 0xf, 0xf, true));
}
template<int CTRL>
__device__ __forceinline__ float dpp_ident(float v, float ident) { // invalid -> ident
  return __builtin_bit_cast(float,
    __builtin_amdgcn_update_dpp(__builtin_bit_cast(int, ident),
                                __builtin_bit_cast(int, v), CTRL, 0xf, 0xf, false));
}
__device__ __forceinline__ float rl63(float v) {
  return __builtin_bit_cast(float,
    __builtin_amdgcn_readlane(__builtin_bit_cast(int, v), 63));
}

__device__ __forceinline__ float wave_sum(float v) {
  v += dpp_zero<0x111>(v); v += dpp_zero<0x112>(v); v += dpp_zero<0x114>(v);
  v += dpp_zero<0x118>(v); v += dpp_zero<0x142>(v); v += dpp_zero<0x143>(v);
  return rl63(v);
}
// Fused init+probe reduction: 2 maxes + 4 sums, interleaved per level ->
// one serial chain latency for all six wave-uniform results.
__device__ __forceinline__ void wave_red6(float& a, float& b, float& s1,
                                          float& s2, float& s3, float& s4) {
  const float NI = -3.4028235e38f;
#define RED6_STEP(CT) \
  a = fmaxf(a, dpp_ident<CT>(a, NI)); b = fmaxf(b, dpp_ident<CT>(b, NI)); \
  s1 += dpp_zero<CT>(s1); s2 += dpp_zero<CT>(s2); \
  s3 += dpp_zero<CT>(s3); s4 += dpp_zero<CT>(s4);
  RED6_STEP(0x111) RED6_STEP(0x112) RED6_STEP(0x114)
  RED6_STEP(0x118) RED6_STEP(0x142) RED6_STEP(0x143)
#undef RED6_STEP
  a = rl63(a); b = rl63(b);
  s1 = rl63(s1); s2 = rl63(s2); s3 = rl63(s3); s4 = rl63(s4);
}
// phase 2: one f64 sum + one f32 sum, interleaved
__device__ __forceinline__ void wave_sumd_f(double& A, float& c) {
#define SUMD_STEP(CT) { \
  unsigned long long xa = __builtin_bit_cast(unsigned long long, A); \
  int al = __builtin_amdgcn_update_dpp(0, (int)(unsigned)xa, CT, 0xf, 0xf, true); \
  int ah = __builtin_amdgcn_update_dpp(0, (int)(xa >> 32),   CT, 0xf, 0xf, true); \
  c += dpp_zero<CT>(c); \
  A += __builtin_bit_cast(double, ((unsigned long long)(unsigned)ah << 32) | (unsigned)al); }
  SUMD_STEP(0x111) SUMD_STEP(0x112) SUMD_STEP(0x114)
  SUMD_STEP(0x118) SUMD_STEP(0x142) SUMD_STEP(0x143)
#undef SUMD_STEP
  { unsigned long long x = __builtin_bit_cast(unsigned long long, A);
    int l = __builtin_amdgcn_readlane((int)(unsigned)x, 63);
    int h = __builtin_amdgcn_readlane((int)(x >> 32), 63);
    A = __builtin_bit_cast(double, ((unsigned long long)(unsigned)h << 32) | (unsigned)l); }
  c = rl63(c);
}

__global__ __launch_bounds__(64)
void csparsemax_kernel(const float* __restrict__ z, const float* __restrict__ u,
                       float* __restrict__ out, int B) {
  constexpr int K = 1024;
  const int lane = threadIdx.x & 63;
  const int row = blockIdx.x;
  if (row >= B) return;
  const size_t base = (size_t)row * (size_t)K;

  // --- load 16 elems/lane as 4x float4, coalesced ---
  float zf[16], uf[16];
  const vfloat4* z4p = (const vfloat4*)(z + base);
  const vfloat4* u4p = (const vfloat4*)(u + base);
  #pragma unroll
  for (int j = 0; j < 4; ++j) {
    vfloat4 a = z4p[j * 64 + lane];
    vfloat4 b = u4p[j * 64 + lane];
    zf[j*4+0] = a.x; zf[j*4+1] = a.y; zf[j*4+2] = a.z; zf[j*4+3] = a.w;
    uf[j*4+0] = b.x; uf[j*4+1] = b.y; uf[j*4+2] = b.z; uf[j*4+3] = b.w;
  }

  // --- fused init + absolute-probe classify (one pass, one DPP chain) ---
  const float P1 = 3.10f, P2 = 2.80f, P3 = 2.55f, P4 = 2.25f;
  float a = -3.4028235e38f, m = -3.4028235e38f;
  float A1 = 0.f, A2 = 0.f, A3 = 0.f, A4 = 0.f;
  #pragma unroll
  for (int t = 0; t < 16; ++t) {
    a = fmaxf(a, uf[t] - zf[t]);    // lo = -max(u-z) = min(z-u)
    m = fmaxf(m, zf[t]);
    A1 += fminf(fmaxf(zf[t] - P1, 0.f), uf[t]);   // v_med3_f32 each
    A2 += fminf(fmaxf(zf[t] - P2, 0.f), uf[t]);
    A3 += fminf(fmaxf(zf[t] - P3, 0.f), uf[t]);
    A4 += fminf(fmaxf(zf[t] - P4, 0.f), uf[t]);
  }
  wave_red6(a, m, A1, A2, A3, A4);
  float lo = -a, hi = m;
  const double glo = (double)lo, ghi = (double)hi;
  float gh = -1.f;                                // true g(hi) = 0 - 1
  {
    const float g1 = A1 - 1.f, g2 = A2 - 1.f, g3 = A3 - 1.f, g4 = A4 - 1.f;
    // g non-increasing in tau; P1 > P2 > P3 > P4. Narrow only on sign flips;
    // guards keep the bracket valid when a probe lies outside [lo, hi].
    if (g1 >= 0.f)      { lo = fmaxf(lo, P1); }
    else if (g2 >= 0.f) { lo = fmaxf(lo, P2); if (P1 < hi) { hi = P1; gh = g1; } }
    else if (g3 >= 0.f) { lo = fmaxf(lo, P3); if (P2 < hi) { hi = P2; gh = g2; } }
    else if (g4 >= 0.f) { lo = fmaxf(lo, P4); if (P3 < hi) { hi = P3; gh = g3; } }
    else                {                     if (P4 < hi) { hi = P4; gh = g4; } }
  }

  // --- phase 1: secant on g(tau) = sum med3(z-tau,0,u) - 1 ---
  float t_prev = hi, g_prev = gh;
  float tau = 0.5f * (lo + hi);                  // midpoint of narrowed bracket
  for (int it = 0; it < 48; ++it) {
    float f0 = 0.f, f1 = 0.f, f2 = 0.f, f3 = 0.f;
    #pragma unroll
    for (int t = 0; t < 16; t += 4) {            // v_med3_f32 per elem
      f0 += fminf(fmaxf(zf[t+0] - tau, 0.f), uf[t+0]);
      f1 += fminf(fmaxf(zf[t+1] - tau, 0.f), uf[t+1]);
      f2 += fminf(fmaxf(zf[t+2] - tau, 0.f), uf[t+2]);
      f3 += fminf(fmaxf(zf[t+3] - tau, 0.f), uf[t+3]);
    }
    float g = wave_sum((f0 + f1) + (f2 + f3)) - 1.f;
    if (g == 0.f) break;
    if (g > 0.f) lo = tau; else hi = tau;
    // secant through (t_prev,g_prev),(tau,g); out-of-bracket -> midpoint
    float cand = (tau * g_prev - t_prev * g) / (g_prev - g);
    t_prev = tau; g_prev = g;
    float next = (cand > lo && cand < hi) ? cand : 0.5f * (lo + hi);
    if (next == tau) break;                      // f32 resolution reached
    tau = next;
  }

  // --- phase 2: f64 segment-Newton polish, GLOBAL bracket (exactness) ---
  double dlo = glo, dhi = ghi, taud = (double)tau;
  for (int it = 0; it < 24; ++it) {
    double Sd = 0.0;
    float Cf = 0.f;                              // count exact in f32
    #pragma unroll
    for (int t = 0; t < 16; ++t) {
      double x = (double)zf[t] - taud;
      double ud = (double)uf[t];
      if (x >= ud)      { Sd += ud; }
      else if (x > 0.0) { Sd += (double)zf[t]; Cf += 1.f; }
    }
    wave_sumd_f(Sd, Cf);
    double C = (double)Cf;
    double f = Sd - C * taud;
    if (f == 1.0 && C > 0.5) break;
    if (f > 1.0) dlo = taud; else dhi = taud;
    double next;
    if (C > 0.5) {
      double cand = (Sd - 1.0) / C;              // exact segment root
      if (cand == taud) break;
      next = (cand > dlo && cand < dhi) ? cand : 0.5 * (dlo + dhi);
    } else {
      next = 0.5 * (dlo + dhi);
    }
    if (next == taud) break;
    taud = next;
  }

  // --- epilogue: p/val in f32, regions via f64 compares, NT stores ---
  float* out_p = out;
  float* out_r = out + (size_t)B * (size_t)K;
  float* out_t = out + 2ull * (size_t)B * (size_t)K;
  float* out_v = out_t + B;

  const float tf = (float)taud;
  float vloc = 0.f;
  #pragma unroll
  for (int j = 0; j < 4; ++j) {
    vfloat4 p4v, r4v;
    #pragma unroll
    for (int q = 0; q < 4; ++q) {
      int t = j * 4 + q;
      float pf = fminf(fmaxf(zf[t] - tf, 0.f), uf[t]);   // v_med3_f32
      float d = pf - zf[t];
      vloc = fmaf(d, d, vloc);
      double xd = (double)zf[t] - taud;                  // numpy-exact bounds
      float rg = (xd <= 0.0) ? 0.f : ((xd >= (double)uf[t]) ? 2.f : 1.f);
      p4v[q] = pf;
      r4v[q] = rg;
    }
    __builtin_nontemporal_store(p4v, &((vfloat4*)(out_p + base))[j * 64 + lane]);
    __builtin_nontemporal_store(r4v, &((vfloat4*)(out_r + base))[j * 64 + lane]);
  }

  float vtot = wave_sum(vloc);
  if (lane == 0) {
    out_t[row] = tf;
    out_v[row] = 0.5f * vtot;
  }
}

extern "C" void kernel_launch(void* const* d_in, const int* in_sizes, int n_in,
                              void* d_out, int out_size, void* d_ws, size_t ws_size,
                              hipStream_t stream) {
  const float* z = (const float*)d_in[0];
  const float* u = (const float*)d_in[1];
  float* out = (float*)d_out;
  const int K = 1024;
  const int B = in_sizes[0] / K;
  csparsemax_kernel<<<B, 64, 0, stream>>>(z, u, out, B);
}

// Round 16
// 30.776 us; speedup vs baseline: 1.1429x; 1.0154x over previous
//
#include <hip/hip_runtime.h>

// Constrained sparsemax: p = clip(z - tau, 0, u), tau s.t. sum p = 1.
// R15 structure (best measured 31.25us): 8192 one-wave blocks, fused
// init+absolute-probe pass with ONE interleaved DPP chain, secant phase-1
// on f via med3 (one DPP chain/iter), f64 segment-Newton polish on the
// GLOBAL bracket, f32 epilogue with f64 region compares, NT stores.
// R16 changes (fewer secant evals, ~zero added serial latency):
//  - SIX absolute probes {2.95,2.81,2.70,2.59,2.46,2.28} (denser where
//    tau* ~ 2.6-2.75 +/- 0.15 actually lands for z~N(0,1),K=1024) ->
//    post-probe window ~0.11-0.18 (~15 breakpoints).
//  - carry TRUE g-values (gl, gh) from the ladder; seed phase 1 at the
//    false-position point instead of the midpoint.
// Probe placement cannot affect correctness: narrowing only on observed
// sign flips; phase 2 re-solves from the GLOBAL bracket.

typedef float vfloat4 __attribute__((ext_vector_type(4)));

template<int CTRL>
__device__ __forceinline__ float dpp_zero(float v) {   // invalid lanes -> 0
  return __builtin_bit_cast(float,
    __builtin_amdgcn_update_dpp(0, __builtin_bit_cast(int, v), CTRL, 0xf, 0xf, true));
}
template<int CTRL>
__device__ __forceinline__ float dpp_ident(float v, float ident) { // invalid -> ident
  return __builtin_bit_cast(float,
    __builtin_amdgcn_update_dpp(__builtin_bit_cast(int, ident),
                                __builtin_bit_cast(int, v), CTRL, 0xf, 0xf, false));
}
__device__ __forceinline__ float rl63(float v) {
  return __builtin_bit_cast(float,
    __builtin_amdgcn_readlane(__builtin_bit_cast(int, v), 63));
}

__device__ __forceinline__ float wave_sum(float v) {
  v += dpp_zero<0x111>(v); v += dpp_zero<0x112>(v); v += dpp_zero<0x114>(v);
  v += dpp_zero<0x118>(v); v += dpp_zero<0x142>(v); v += dpp_zero<0x143>(v);
  return rl63(v);
}
// Fused init+probe reduction: 2 maxes + 6 sums, interleaved per level ->
// one serial chain latency for all eight wave-uniform results.
__device__ __forceinline__ void wave_red8(float& a, float& b,
                                          float& s1, float& s2, float& s3,
                                          float& s4, float& s5, float& s6) {
  const float NI = -3.4028235e38f;
#define RED8_STEP(CT) \
  a = fmaxf(a, dpp_ident<CT>(a, NI)); b = fmaxf(b, dpp_ident<CT>(b, NI)); \
  s1 += dpp_zero<CT>(s1); s2 += dpp_zero<CT>(s2); s3 += dpp_zero<CT>(s3); \
  s4 += dpp_zero<CT>(s4); s5 += dpp_zero<CT>(s5); s6 += dpp_zero<CT>(s6);
  RED8_STEP(0x111) RED8_STEP(0x112) RED8_STEP(0x114)
  RED8_STEP(0x118) RED8_STEP(0x142) RED8_STEP(0x143)
#undef RED8_STEP
  a = rl63(a); b = rl63(b);
  s1 = rl63(s1); s2 = rl63(s2); s3 = rl63(s3);
  s4 = rl63(s4); s5 = rl63(s5); s6 = rl63(s6);
}
// phase 2: one f64 sum + one f32 sum, interleaved
__device__ __forceinline__ void wave_sumd_f(double& A, float& c) {
#define SUMD_STEP(CT) { \
  unsigned long long xa = __builtin_bit_cast(unsigned long long, A); \
  int al = __builtin_amdgcn_update_dpp(0, (int)(unsigned)xa, CT, 0xf, 0xf, true); \
  int ah = __builtin_amdgcn_update_dpp(0, (int)(xa >> 32),   CT, 0xf, 0xf, true); \
  c += dpp_zero<CT>(c); \
  A += __builtin_bit_cast(double, ((unsigned long long)(unsigned)ah << 32) | (unsigned)al); }
  SUMD_STEP(0x111) SUMD_STEP(0x112) SUMD_STEP(0x114)
  SUMD_STEP(0x118) SUMD_STEP(0x142) SUMD_STEP(0x143)
#undef SUMD_STEP
  { unsigned long long x = __builtin_bit_cast(unsigned long long, A);
    int l = __builtin_amdgcn_readlane((int)(unsigned)x, 63);
    int h = __builtin_amdgcn_readlane((int)(x >> 32), 63);
    A = __builtin_bit_cast(double, ((unsigned long long)(unsigned)h << 32) | (unsigned)l); }
  c = rl63(c);
}

__global__ __launch_bounds__(64)
void csparsemax_kernel(const float* __restrict__ z, const float* __restrict__ u,
                       float* __restrict__ out, int B) {
  constexpr int K = 1024;
  const int lane = threadIdx.x & 63;
  const int row = blockIdx.x;
  if (row >= B) return;
  const size_t base = (size_t)row * (size_t)K;

  // --- load 16 elems/lane as 4x float4, coalesced ---
  float zf[16], uf[16];
  const vfloat4* z4p = (const vfloat4*)(z + base);
  const vfloat4* u4p = (const vfloat4*)(u + base);
  #pragma unroll
  for (int j = 0; j < 4; ++j) {
    vfloat4 a = z4p[j * 64 + lane];
    vfloat4 b = u4p[j * 64 + lane];
    zf[j*4+0] = a.x; zf[j*4+1] = a.y; zf[j*4+2] = a.z; zf[j*4+3] = a.w;
    uf[j*4+0] = b.x; uf[j*4+1] = b.y; uf[j*4+2] = b.z; uf[j*4+3] = b.w;
  }

  // --- fused init + 6 absolute probes (one pass, one DPP chain) ---
  const float P1 = 2.95f, P2 = 2.81f, P3 = 2.70f,
              P4 = 2.59f, P5 = 2.46f, P6 = 2.28f;
  float a = -3.4028235e38f, m = -3.4028235e38f;
  float A1 = 0.f, A2 = 0.f, A3 = 0.f, A4 = 0.f, A5 = 0.f, A6 = 0.f;
  #pragma unroll
  for (int t = 0; t < 16; ++t) {
    a = fmaxf(a, uf[t] - zf[t]);    // lo = -max(u-z) = min(z-u)
    m = fmaxf(m, zf[t]);
    A1 += fminf(fmaxf(zf[t] - P1, 0.f), uf[t]);   // v_med3_f32 each
    A2 += fminf(fmaxf(zf[t] - P2, 0.f), uf[t]);
    A3 += fminf(fmaxf(zf[t] - P3, 0.f), uf[t]);
    A4 += fminf(fmaxf(zf[t] - P4, 0.f), uf[t]);
    A5 += fminf(fmaxf(zf[t] - P5, 0.f), uf[t]);
    A6 += fminf(fmaxf(zf[t] - P6, 0.f), uf[t]);
  }
  wave_red8(a, m, A1, A2, A3, A4, A5, A6);
  float lo = -a, hi = m;
  const double glo = (double)lo, ghi = (double)hi;
  float gl = 1.0e30f;                             // g(lo) >= su-1 >= 0 (unused magnitude)
  float gh = -1.f;                                // true g(hi)
  {
    const float g1 = A1 - 1.f, g2 = A2 - 1.f, g3 = A3 - 1.f;
    const float g4 = A4 - 1.f, g5 = A5 - 1.f, g6 = A6 - 1.f;
    // g non-increasing in tau; P1 > P2 > ... > P6. Narrow only on true sign
    // flips; guards keep the bracket valid if a probe lies outside [lo,hi].
    if (g1 >= 0.f)      { if (P1 > lo) { lo = P1; gl = g1; } }
    else if (g2 >= 0.f) { if (P2 > lo) { lo = P2; gl = g2; }
                          if (P1 < hi) { hi = P1; gh = g1; } }
    else if (g3 >= 0.f) { if (P3 > lo) { lo = P3; gl = g3; }
                          if (P2 < hi) { hi = P2; gh = g2; } }
    else if (g4 >= 0.f) { if (P4 > lo) { lo = P4; gl = g4; }
                          if (P3 < hi) { hi = P3; gh = g3; } }
    else if (g5 >= 0.f) { if (P5 > lo) { lo = P5; gl = g5; }
                          if (P4 < hi) { hi = P4; gh = g4; } }
    else if (g6 >= 0.f) { if (P6 > lo) { lo = P6; gl = g6; }
                          if (P5 < hi) { hi = P5; gh = g5; } }
    else                { if (P6 < hi) { hi = P6; gh = g6; } }
  }

  // --- phase 1: secant on g(tau) = sum med3(z-tau,0,u) - 1 ---
  float t_prev = hi, g_prev = gh;
  // seed: false position when both endpoint g's are finite/known, else midpoint
  float tau;
  if (gl < 1.0e29f) {
    tau = (lo * gh - hi * gl) / (gh - gl);
    if (!(tau > lo && tau < hi)) tau = 0.5f * (lo + hi);
  } else {
    tau = 0.5f * (lo + hi);
  }
  for (int it = 0; it < 48; ++it) {
    float f0 = 0.f, f1 = 0.f, f2 = 0.f, f3 = 0.f;
    #pragma unroll
    for (int t = 0; t < 16; t += 4) {            // v_med3_f32 per elem
      f0 += fminf(fmaxf(zf[t+0] - tau, 0.f), uf[t+0]);
      f1 += fminf(fmaxf(zf[t+1] - tau, 0.f), uf[t+1]);
      f2 += fminf(fmaxf(zf[t+2] - tau, 0.f), uf[t+2]);
      f3 += fminf(fmaxf(zf[t+3] - tau, 0.f), uf[t+3]);
    }
    float g = wave_sum((f0 + f1) + (f2 + f3)) - 1.f;
    if (g == 0.f) break;
    if (g > 0.f) lo = tau; else hi = tau;
    // secant through (t_prev,g_prev),(tau,g); out-of-bracket -> midpoint
    float cand = (tau * g_prev - t_prev * g) / (g_prev - g);
    t_prev = tau; g_prev = g;
    float next = (cand > lo && cand < hi) ? cand : 0.5f * (lo + hi);
    if (next == tau) break;                      // f32 resolution reached
    tau = next;
  }

  // --- phase 2: f64 segment-Newton polish, GLOBAL bracket (exactness) ---
  double dlo = glo, dhi = ghi, taud = (double)tau;
  for (int it = 0; it < 24; ++it) {
    double Sd = 0.0;
    float Cf = 0.f;                              // count exact in f32
    #pragma unroll
    for (int t = 0; t < 16; ++t) {
      double x = (double)zf[t] - taud;
      double ud = (double)uf[t];
      if (x >= ud)      { Sd += ud; }
      else if (x > 0.0) { Sd += (double)zf[t]; Cf += 1.f; }
    }
    wave_sumd_f(Sd, Cf);
    double C = (double)Cf;
    double f = Sd - C * taud;
    if (f == 1.0 && C > 0.5) break;
    if (f > 1.0) dlo = taud; else dhi = taud;
    double next;
    if (C > 0.5) {
      double cand = (Sd - 1.0) / C;              // exact segment root
      if (cand == taud) break;
      next = (cand > dlo && cand < dhi) ? cand : 0.5 * (dlo + dhi);
    } else {
      next = 0.5 * (dlo + dhi);
    }
    if (next == taud) break;
    taud = next;
  }

  // --- epilogue: p/val in f32, regions via f64 compares, NT stores ---
  float* out_p = out;
  float* out_r = out + (size_t)B * (size_t)K;
  float* out_t = out + 2ull * (size_t)B * (size_t)K;
  float* out_v = out_t + B;

  const float tf = (float)taud;
  float vloc = 0.f;
  #pragma unroll
  for (int j = 0; j < 4; ++j) {
    vfloat4 p4v, r4v;
    #pragma unroll
    for (int q = 0; q < 4; ++q) {
      int t = j * 4 + q;
      float pf = fminf(fmaxf(zf[t] - tf, 0.f), uf[t]);   // v_med3_f32
      float d = pf - zf[t];
      vloc = fmaf(d, d, vloc);
      double xd = (double)zf[t] - taud;                  // numpy-exact bounds
      float rg = (xd <= 0.0) ? 0.f : ((xd >= (double)uf[t]) ? 2.f : 1.f);
      p4v[q] = pf;
      r4v[q] = rg;
    }
    __builtin_nontemporal_store(p4v, &((vfloat4*)(out_p + base))[j * 64 + lane]);
    __builtin_nontemporal_store(r4v, &((vfloat4*)(out_r + base))[j * 64 + lane]);
  }

  float vtot = wave_sum(vloc);
  if (lane == 0) {
    out_t[row] = tf;
    out_v[row] = 0.5f * vtot;
  }
}

extern "C" void kernel_launch(void* const* d_in, const int* in_sizes, int n_in,
                              void* d_out, int out_size, void* d_ws, size_t ws_size,
                              hipStream_t stream) {
  const float* z = (const float*)d_in[0];
  const float* u = (const float*)d_in[1];
  float* out = (float*)d_out;
  const int K = 1024;
  const int B = in_sizes[0] / K;
  csparsemax_kernel<<<B, 64, 0, stream>>>(z, u, out, B);
}